// Round 11
// baseline (622.633 us; speedup 1.0000x reference)
//
#include <hip/hip_runtime.h>
#include <cstddef>
#include <cstdint>

typedef __attribute__((ext_vector_type(8))) short bf16x8;
typedef __attribute__((ext_vector_type(4))) float f32x4;

__device__ __forceinline__ float lrelu_f(float v) { return v > 0.f ? v : 0.2f * v; }

__device__ __forceinline__ unsigned short f2bf_rne(float f) {
  unsigned u = __float_as_uint(f);
  return (unsigned short)((u + 0x7fffu + ((u >> 16) & 1u)) >> 16);
}
__device__ __forceinline__ float bf2f(unsigned short h) {
  return __uint_as_float((unsigned)h << 16);
}

// ------- prep: pad x [B,N,6] -> [B,N,16] (fp32 + bf16 hi/lo), compute xx -----
__global__ void prepx_kernel(const float* __restrict__ x, float* __restrict__ xpad,
                             unsigned short* __restrict__ xph,
                             unsigned short* __restrict__ xpl,
                             float* __restrict__ xx) {
  int p = blockIdx.x * 256 + threadIdx.x;  // 0..16383
  const float* xp = x + (size_t)p * 6;
  float v[6];
  float s = 0.f;
#pragma unroll
  for (int c = 0; c < 6; ++c) { v[c] = xp[c]; s = fmaf(v[c], v[c], s); }
  float* o = xpad + (size_t)p * 16;
  unsigned short* oh = xph + (size_t)p * 16;
  unsigned short* ol = xpl + (size_t)p * 16;
#pragma unroll
  for (int c = 0; c < 6; ++c) {
    o[c] = v[c];
    unsigned short h = f2bf_rne(v[c]);
    oh[c] = h;
    ol[c] = f2bf_rne(v[c] - bf2f(h));
  }
#pragma unroll
  for (int c = 6; c < 16; ++c) { o[c] = 0.f; oh[c] = 0; ol[c] = 0; }
  xx[p] = s;
}

// ---------------- Wc prep: [2out, dpad]; rows 0..out-1 = W_a, out.. = W_b - W_a
__global__ void wcprep_kernel(const float* __restrict__ W, float* __restrict__ Wc,
                              int out, int d, int dpad) {
  int i = blockIdx.x * 256 + threadIdx.x;
  if (i >= 2 * out * dpad) return;
  int j = i / dpad, c = i - j * dpad;
  float v = 0.f;
  if (c < d) {
    v = (j < out) ? W[j * 2 * d + c]
                  : (W[(j - out) * 2 * d + d + c] - W[(j - out) * 2 * d + c]);
  }
  Wc[i] = v;
}

// ---------------- W4 -> bf16 hi/lo split ------------------------------------
__global__ void w4prep_kernel(const float* __restrict__ W4,
                              unsigned short* __restrict__ W4h,
                              unsigned short* __restrict__ W4l) {
  int i = blockIdx.x * 256 + threadIdx.x;  // 0..524287
  float v = W4[i];
  unsigned short h = f2bf_rne(v);
  W4h[i] = h;
  W4l[i] = f2bf_rne(v - bf2f(h));
}

// ---- fused dist+top20: block = 16 rows x 1024 cols of one batch -------------
// S[i][j] = 2*dot(F_i,F_j) - xx_j  (row-constant -xx_i dropped: rank-invariant)
// dot via 3-pass bf16 MFMA (hh + hl + lh). Then ballot-radix top-20 per row.
// R11: LDS trimmed below 2-block threshold (xxs removed) + dual col-chunk ILP.
template <int DPAD, int KPAD>
__global__ __launch_bounds__(512) void disttopk_kernel(
    const unsigned short* __restrict__ Fh, const unsigned short* __restrict__ Fl,
    int fstride, int foff, const float* __restrict__ xx, int* __restrict__ idx) {
  constexpr int LSTR = KPAD + 8;   // ushorts; keeps 16B align, breaks bank aliasing
  constexpr int SSTR = 1028;       // floats; +4 pad -> S writes 2-way only
  __shared__ unsigned short rFh[16 * LSTR];
  __shared__ unsigned short rFl[16 * LSTR];
  __shared__ float S[16 * SSTR];
  int tid = threadIdx.x;
  int b = blockIdx.y, r0 = blockIdx.x * 16;
  int rowg0 = b * 1024 + r0;

  // stage the 16 A-rows (zero-padded to KPAD)
  constexpr int KC = KPAD / 8;
  for (int e = tid; e < 16 * KC; e += 512) {
    int row = e / KC, kc = e - row * KC;
    uint4 h = {0, 0, 0, 0}, l = {0, 0, 0, 0};
    if (kc * 8 < DPAD) {
      size_t src = (size_t)(rowg0 + row) * fstride + foff + kc * 8;
      h = *(const uint4*)(Fh + src);
      l = *(const uint4*)(Fl + src);
    }
    *(uint4*)(rFh + row * LSTR + kc * 8) = h;
    *(uint4*)(rFl + row * LSTR + kc * 8) = l;
  }
  __syncthreads();

  int wave = tid >> 6, lane = tid & 63;
  int l15 = lane & 15, l4 = lane >> 4;

  // A-fragments: loop-invariant, load once from LDS
  bf16x8 ah[KPAD / 32], al[KPAD / 32];
#pragma unroll
  for (int ks = 0; ks < KPAD / 32; ++ks) {
    ah[ks] = *(const bf16x8*)(rFh + l15 * LSTR + ks * 32 + l4 * 8);
    al[ks] = *(const bf16x8*)(rFl + l15 * LSTR + ks * 32 + l4 * 8);
  }

  const float* xxb = xx + b * 1024;

  // 4 pair-iterations; wave w owns cols {p*256 + w*16 .. +15} and {+128}.
  // Two independent acc sets double load- and MFMA-level parallelism.
  for (int p = 0; p < 4; ++p) {
    int c0 = p * 256 + wave * 16;
    int c1 = c0 + 128;
    size_t sb0 = (size_t)(b * 1024 + c0 + l15) * fstride + foff + l4 * 8;
    size_t sb1 = (size_t)(b * 1024 + c1 + l15) * fstride + foff + l4 * 8;
    f32x4 aA0 = {}, aB0 = {}, aA1 = {}, aB1 = {};
#pragma unroll
    for (int ks = 0; ks < KPAD / 32; ++ks) {
      bf16x8 bh0 = {}, bl0 = {}, bh1 = {}, bl1 = {};
      if (ks * 32 + l4 * 8 < DPAD) {  // guards only layer0's K-pad region
        bh0 = *(const bf16x8*)(Fh + sb0 + ks * 32);
        bl0 = *(const bf16x8*)(Fl + sb0 + ks * 32);
        bh1 = *(const bf16x8*)(Fh + sb1 + ks * 32);
        bl1 = *(const bf16x8*)(Fl + sb1 + ks * 32);
      }
      aA0 = __builtin_amdgcn_mfma_f32_16x16x32_bf16(ah[ks], bh0, aA0, 0, 0, 0);
      aA1 = __builtin_amdgcn_mfma_f32_16x16x32_bf16(ah[ks], bh1, aA1, 0, 0, 0);
      aB0 = __builtin_amdgcn_mfma_f32_16x16x32_bf16(ah[ks], bl0, aB0, 0, 0, 0);
      aB1 = __builtin_amdgcn_mfma_f32_16x16x32_bf16(ah[ks], bl1, aB1, 0, 0, 0);
      aA0 = __builtin_amdgcn_mfma_f32_16x16x32_bf16(al[ks], bh0, aA0, 0, 0, 0);
      aA1 = __builtin_amdgcn_mfma_f32_16x16x32_bf16(al[ks], bh1, aA1, 0, 0, 0);
    }
    float xc0 = xxb[c0 + l15], xc1 = xxb[c1 + l15];
#pragma unroll
    for (int r = 0; r < 4; ++r) {
      S[(l4 * 4 + r) * SSTR + c0 + l15] = 2.f * (aA0[r] + aB0[r]) - xc0;
      S[(l4 * 4 + r) * SSTR + c1 + l15] = 2.f * (aA1[r] + aB1[r]) - xc1;
    }
  }
  __syncthreads();

  // top-20 per row: wave handles rows {wave, wave+8}
  unsigned long long lanebit = 1ull << lane;
  for (int rr = wave; rr < 16; rr += 8) {
    unsigned u[16];
#pragma unroll
    for (int j = 0; j < 16; ++j) {
      unsigned bits = __float_as_uint(S[rr * SSTR + j * 64 + lane]);
      unsigned m = (unsigned)((int)bits >> 31);
      u[j] = bits ^ (m | 0x80000000u);  // order-preserving map
    }
    unsigned X = 0;
    for (int bit = 31; bit >= 0; --bit) {
      unsigned Xt = X | (1u << bit);
      int c = 0;
#pragma unroll
      for (int j = 0; j < 16; ++j) c += __popcll(__ballot(u[j] >= Xt));
      if (c >= 20) X = Xt;
    }
    const unsigned T = X;
    int* op = idx + (size_t)(rowg0 + rr) * 20;
    int base = 0;
#pragma unroll
    for (int j = 0; j < 16; ++j) {
      unsigned long long m = __ballot(u[j] > T);
      int before = __popcll(m & (lanebit - 1ull));
      if (m & lanebit) op[base + before] = j * 64 + lane;
      base += __popcll(m);
    }
#pragma unroll
    for (int j = 0; j < 16; ++j) {
      unsigned long long m = __ballot(u[j] == T);
      int before = __popcll(m & (lanebit - 1ull));
      int pos = base + before;
      if ((m & lanebit) && pos < 20) op[pos] = j * 64 + lane;
      base += __popcll(m);
    }
  }
}

// ---------------- AB = F @ Wc^T : [16384, 2out] --------------------------------
__global__ __launch_bounds__(256) void ab_kernel(
    const float* __restrict__ F, int stride, int off, int dpad,
    const float* __restrict__ Wc, int twoout, float* __restrict__ AB) {
  int pb = blockIdx.x * 64, cb = blockIdx.y * 64;
  __shared__ __align__(16) float As[16][68];
  __shared__ __align__(16) float Bs[16][68];
  int tid = threadIdx.x;
  int tx = tid & 15, ty = tid >> 4;
  int lp = tid >> 2, lk = (tid & 3) * 4;
  float acc[4][4] = {};
  for (int k0 = 0; k0 < dpad; k0 += 16) {
    float4 av = *(const float4*)(F + (size_t)(pb + lp) * stride + off + k0 + lk);
    float4 bv = *(const float4*)(Wc + (size_t)(cb + lp) * dpad + k0 + lk);
    __syncthreads();
    As[lk + 0][lp] = av.x; As[lk + 1][lp] = av.y; As[lk + 2][lp] = av.z; As[lk + 3][lp] = av.w;
    Bs[lk + 0][lp] = bv.x; Bs[lk + 1][lp] = bv.y; Bs[lk + 2][lp] = bv.z; Bs[lk + 3][lp] = bv.w;
    __syncthreads();
#pragma unroll
    for (int kk = 0; kk < 16; ++kk) {
      float4 a4 = *(const float4*)&As[kk][ty * 4];
      float4 b4 = *(const float4*)&Bs[kk][tx * 4];
      float ar[4] = {a4.x, a4.y, a4.z, a4.w};
      float br[4] = {b4.x, b4.y, b4.z, b4.w};
#pragma unroll
      for (int i = 0; i < 4; ++i)
#pragma unroll
        for (int j = 0; j < 4; ++j) acc[i][j] = fmaf(ar[i], br[j], acc[i][j]);
    }
  }
#pragma unroll
  for (int i = 0; i < 4; ++i) {
    float4 o = {acc[i][0], acc[i][1], acc[i][2], acc[i][3]};
    *(float4*)(AB + (size_t)(pb + ty * 4 + i) * twoout + cb + tx * 4) = o;
  }
}

// ------- out[p,o] = max_t lrelu(A[idx[p][t],o] + Bc[p,o]); bf16 hi/lo too ----
__global__ void gathermax_kernel(const float* __restrict__ AB, const int* __restrict__ idx,
                                 float* __restrict__ catb,
                                 unsigned short* __restrict__ cat_hi,
                                 unsigned short* __restrict__ cat_lo,
                                 float* __restrict__ xx,
                                 int out, int catoff, int needxx) {
  int tid = threadIdx.x;
  int q = tid / out, o = tid - q * out;
  int ppb = 256 / out;
  int p = blockIdx.x * ppb + q;  // global point 0..16383
  int twoout = out * 2;
  const int* ip = idx + (size_t)p * 20;
  float bias = AB[(size_t)p * twoout + out + o];
  int bbase = p & ~1023;
  float m = -3.402823466e38f;
#pragma unroll
  for (int t = 0; t < 20; ++t) {
    int j = ip[t];
    float v = AB[(size_t)(bbase + j) * twoout + o] + bias;
    v = v > 0.f ? v : 0.2f * v;
    m = fmaxf(m, v);
  }
  size_t ci = (size_t)p * 512 + catoff + o;
  catb[ci] = m;
  unsigned short h = f2bf_rne(m);
  cat_hi[ci] = h;
  cat_lo[ci] = f2bf_rne(m - bf2f(h));
  if (needxx) {
    __shared__ float buf[256];
    buf[tid] = m * m;
    __syncthreads();
    for (int s = out >> 1; s > 0; s >>= 1) {
      if (o < s) buf[tid] += buf[tid + s];
      __syncthreads();
    }
    if (o == 0) xx[p] = buf[tid];
  }
}

// ------- partial[b,nb,o] = max over 64-pt chunk of lrelu(W4 @ cat), bf16x3 MFMA
__global__ __launch_bounds__(256) void gemmmax_kernel(
    const unsigned short* __restrict__ cat_hi, const unsigned short* __restrict__ cat_lo,
    const unsigned short* __restrict__ W4h, const unsigned short* __restrict__ W4l,
    float* __restrict__ partial) {
  int b = blockIdx.z;
  int ob = blockIdx.x * 128;        // o-tile base
  int ny = blockIdx.y;              // n-chunk (64 points)
  int p0 = b * 1024 + ny * 64;      // global point base
  __shared__ __align__(16) unsigned short Ah[128 * 40];
  __shared__ __align__(16) unsigned short Al[128 * 40];
  __shared__ __align__(16) unsigned short Bh[64 * 40];
  __shared__ __align__(16) unsigned short Bl[64 * 40];
  int tid = threadIdx.x;
  int wave = tid >> 6, lane = tid & 63;
  int l15 = lane & 15, l4 = lane >> 4;

  int arow = tid >> 1, ac0 = (tid & 1) * 2;
  int brow = tid >> 2, bc = tid & 3;

  f32x4 acc[2][4] = {};

  for (int k0 = 0; k0 < 512; k0 += 32) {
    uint4 a0 = *(const uint4*)(W4h + (size_t)(ob + arow) * 512 + k0 + ac0 * 8);
    uint4 a1 = *(const uint4*)(W4h + (size_t)(ob + arow) * 512 + k0 + (ac0 + 1) * 8);
    uint4 al0 = *(const uint4*)(W4l + (size_t)(ob + arow) * 512 + k0 + ac0 * 8);
    uint4 al1 = *(const uint4*)(W4l + (size_t)(ob + arow) * 512 + k0 + (ac0 + 1) * 8);
    uint4 b0 = *(const uint4*)(cat_hi + (size_t)(p0 + brow) * 512 + k0 + bc * 8);
    uint4 bl0 = *(const uint4*)(cat_lo + (size_t)(p0 + brow) * 512 + k0 + bc * 8);
    __syncthreads();
    *(uint4*)(Ah + arow * 40 + ac0 * 8) = a0;
    *(uint4*)(Ah + arow * 40 + (ac0 + 1) * 8) = a1;
    *(uint4*)(Al + arow * 40 + ac0 * 8) = al0;
    *(uint4*)(Al + arow * 40 + (ac0 + 1) * 8) = al1;
    *(uint4*)(Bh + brow * 40 + bc * 8) = b0;
    *(uint4*)(Bl + brow * 40 + bc * 8) = bl0;
    __syncthreads();

    bf16x8 ah[2], alr[2], bh[4], blr[4];
#pragma unroll
    for (int m = 0; m < 2; ++m) {
      int r = wave * 32 + m * 16 + l15;
      ah[m] = *(const bf16x8*)(Ah + r * 40 + l4 * 8);
      alr[m] = *(const bf16x8*)(Al + r * 40 + l4 * 8);
    }
#pragma unroll
    for (int n = 0; n < 4; ++n) {
      int r = n * 16 + l15;
      bh[n] = *(const bf16x8*)(Bh + r * 40 + l4 * 8);
      blr[n] = *(const bf16x8*)(Bl + r * 40 + l4 * 8);
    }
#pragma unroll
    for (int m = 0; m < 2; ++m)
#pragma unroll
      for (int n = 0; n < 4; ++n) {
        acc[m][n] = __builtin_amdgcn_mfma_f32_16x16x32_bf16(ah[m], bh[n], acc[m][n], 0, 0, 0);
        acc[m][n] = __builtin_amdgcn_mfma_f32_16x16x32_bf16(ah[m], blr[n], acc[m][n], 0, 0, 0);
        acc[m][n] = __builtin_amdgcn_mfma_f32_16x16x32_bf16(alr[m], bh[n], acc[m][n], 0, 0, 0);
      }
  }

#pragma unroll
  for (int m = 0; m < 2; ++m)
#pragma unroll
    for (int r = 0; r < 4; ++r) {
      float v = lrelu_f(acc[m][0][r]);
      v = fmaxf(v, lrelu_f(acc[m][1][r]));
      v = fmaxf(v, lrelu_f(acc[m][2][r]));
      v = fmaxf(v, lrelu_f(acc[m][3][r]));
      v = fmaxf(v, __shfl_xor(v, 1));
      v = fmaxf(v, __shfl_xor(v, 2));
      v = fmaxf(v, __shfl_xor(v, 4));
      v = fmaxf(v, __shfl_xor(v, 8));
      if (l15 == 0)
        partial[((size_t)(b * 16 + ny) << 10) + ob + wave * 32 + m * 16 + l4 * 4 + r] = v;
    }
}

// ---- zprep: z[b][1088] = [maxpool(partial) | y-MLP]; seed out[b] = L2b ------
__global__ __launch_bounds__(256) void zprep_kernel(
    const float* __restrict__ partial, const float* __restrict__ y,
    const float* __restrict__ F0w, const float* __restrict__ F0b,
    const float* __restrict__ F1w, const float* __restrict__ F1b,
    const float* __restrict__ L2b, float* __restrict__ zbuf,
    float* __restrict__ outp) {
  int b = blockIdx.x, tid = threadIdx.x;
  __shared__ float ye0[16];
  for (int o = tid; o < 1024; o += 256) {
    float m = -3.402823466e38f;
#pragma unroll
    for (int nb = 0; nb < 16; ++nb)
      m = fmaxf(m, partial[((size_t)(b * 16 + nb) << 10) + o]);
    zbuf[(size_t)b * 1088 + o] = m;
  }
  if (tid < 16) {
    float s = F0b[tid];
#pragma unroll
    for (int c = 0; c < 16; ++c) s = fmaf(y[b * 16 + c], F0w[tid * 16 + c], s);
    ye0[tid] = lrelu_f(s);
  }
  __syncthreads();
  if (tid < 64) {
    float s = F1b[tid];
#pragma unroll
    for (int c = 0; c < 16; ++c) s = fmaf(ye0[c], F1w[tid * 16 + c], s);
    zbuf[(size_t)b * 1088 + 1024 + tid] = lrelu_f(s);
  }
  if (tid == 0) outp[b] = L2b[0];
}

// ---- l0: z1[b][512] = lrelu(L0 @ z[b]); 4 threads per output row -----------
__global__ __launch_bounds__(256) void l0_kernel(
    const float* __restrict__ zbuf, const float* __restrict__ L0,
    float* __restrict__ z1buf) {
  int jt = blockIdx.x, b = blockIdx.y, tid = threadIdx.x;
  __shared__ __align__(16) float zs[1088];
  // 1088 floats = 272 float4; 256 threads cover 1024, tid<16 cover the tail.
  *(float4*)&zs[tid * 4] = *(const float4*)&zbuf[(size_t)b * 1088 + tid * 4];
  if (tid < 16)
    *(float4*)&zs[1024 + tid * 4] =
        *(const float4*)&zbuf[(size_t)b * 1088 + 1024 + tid * 4];
  __syncthreads();
  int j = jt * 64 + (tid >> 2), sl = tid & 3;
  const float4* Lr = (const float4*)(L0 + (size_t)j * 1088 + sl * 272);
  const float4* zr = (const float4*)(zs + sl * 272);
  float s = 0.f;
#pragma unroll 8
  for (int c = 0; c < 68; ++c) {
    float4 w = Lr[c], zz = zr[c];
    s = fmaf(w.x, zz.x, s); s = fmaf(w.y, zz.y, s);
    s = fmaf(w.z, zz.z, s); s = fmaf(w.w, zz.w, s);
  }
  s += __shfl_xor(s, 1);
  s += __shfl_xor(s, 2);
  if (sl == 0) z1buf[(size_t)b * 512 + j] = lrelu_f(s);
}

// ---- l1l2: z2 = lrelu(L1 @ z1); out[b] += sum z2*L2w (atomic per block) -----
__global__ __launch_bounds__(256) void l1l2_kernel(
    const float* __restrict__ z1buf, const float* __restrict__ L1,
    const float* __restrict__ L2w, float* __restrict__ outp) {
  int jt = blockIdx.x, b = blockIdx.y, tid = threadIdx.x;
  __shared__ __align__(16) float zs[512];
  if (tid < 128) *(float4*)&zs[tid * 4] = *(const float4*)&z1buf[(size_t)b * 512 + tid * 4];
  __syncthreads();
  int j = jt * 64 + (tid >> 2), sl = tid & 3;
  const float4* Lr = (const float4*)(L1 + (size_t)j * 512 + sl * 128);
  const float4* zr = (const float4*)(zs + sl * 128);
  float s = 0.f;
#pragma unroll 8
  for (int c = 0; c < 32; ++c) {
    float4 w = Lr[c], zz = zr[c];
    s = fmaf(w.x, zz.x, s); s = fmaf(w.y, zz.y, s);
    s = fmaf(w.z, zz.z, s); s = fmaf(w.w, zz.w, s);
  }
  s += __shfl_xor(s, 1);
  s += __shfl_xor(s, 2);
  float v = (sl == 0) ? lrelu_f(s) * L2w[j] : 0.f;
#pragma unroll
  for (int m = 1; m < 64; m <<= 1) v += __shfl_xor(v, m);
  __shared__ float wsum[4];
  if ((tid & 63) == 0) wsum[tid >> 6] = v;
  __syncthreads();
  if (tid == 0) atomicAdd(&outp[b], wsum[0] + wsum[1] + wsum[2] + wsum[3]);
}

extern "C" void kernel_launch(void* const* d_in, const int* in_sizes, int n_in,
                              void* d_out, int out_size, void* d_ws, size_t ws_size,
                              hipStream_t stream) {
  const float* x = (const float*)d_in[0];
  const float* y = (const float*)d_in[1];
  const float* Wl[4] = {(const float*)d_in[2], (const float*)d_in[3],
                        (const float*)d_in[4], (const float*)d_in[5]};
  const float* W4 = (const float*)d_in[6];
  const float* L0 = (const float*)d_in[7];
  const float* L1 = (const float*)d_in[8];
  const float* L2w = (const float*)d_in[9];
  const float* L2b = (const float*)d_in[10];
  const float* F0w = (const float*)d_in[11];
  const float* F0b = (const float*)d_in[12];
  const float* F1w = (const float*)d_in[13];
  const float* F1b = (const float*)d_in[14];

  float* ws = (float*)d_ws;
  float* xpad = ws;                     // 16384*16      = 262144
  float* catb = ws + 262144;            // 16384*512     = 8388608
  // former D region (now unused) hosts the bf16 split of xpad:
  unsigned short* xph = (unsigned short*)(ws + 8650752);   // 16384*16 u16
  unsigned short* xpl = (unsigned short*)(ws + 8781824);   // 16384*16 u16
  float* AB   = ws + 25427968;          // 16384*512     = 8388608
  int*   idx  = (int*)(ws + 33816576);  // 16384*20      = 327680
  float* xx   = ws + 34144256;          // 16384
  float* Wc   = ws + 34160640;          // 512*128       = 65536
  float* part = ws + 34226176;          // 16*16*1024    = 262144
  unsigned short* cat_hi = (unsigned short*)(ws + 34488320);  // 16384*512 u16
  unsigned short* cat_lo = (unsigned short*)(ws + 38682624);  // 16384*512 u16
  unsigned short* W4h    = (unsigned short*)(ws + 42876928);  // 1024*512 u16
  unsigned short* W4l    = (unsigned short*)(ws + 43139072);  // 1024*512 u16
  float* zbuf  = ws + 43401216;         // 16*1088 = 17408
  float* z1buf = ws + 43418624;         // 16*512  = 8192

  prepx_kernel<<<64, 256, 0, stream>>>(x, xpad, xph, xpl, xx);
  w4prep_kernel<<<2048, 256, 0, stream>>>(W4, W4h, W4l);

  struct LC { const float* F; int stride, off, d, dpad, out, catoff, needxx; };
  LC lc[4] = {
      {xpad, 16, 0, 6, 16, 64, 0, 1},
      {catb, 512, 0, 64, 64, 64, 64, 1},
      {catb, 512, 64, 64, 64, 128, 128, 1},
      {catb, 512, 128, 128, 128, 256, 256, 0},
  };
  for (int l = 0; l < 4; ++l) {
    LC c = lc[l];
    int twoout = c.out * 2;
    wcprep_kernel<<<(2 * c.out * c.dpad + 255) / 256, 256, 0, stream>>>(
        Wl[l], Wc, c.out, c.d, c.dpad);
    if (l == 0)
      disttopk_kernel<16, 32><<<dim3(64, 16), 512, 0, stream>>>(
          xph, xpl, 16, 0, xx, idx);
    else if (l == 3)
      disttopk_kernel<128, 128><<<dim3(64, 16), 512, 0, stream>>>(
          cat_hi, cat_lo, 512, 128, xx, idx);
    else
      disttopk_kernel<64, 64><<<dim3(64, 16), 512, 0, stream>>>(
          cat_hi, cat_lo, 512, (l == 1) ? 0 : 64, xx, idx);
    ab_kernel<<<dim3(256, twoout / 64), 256, 0, stream>>>(
        c.F, c.stride, c.off, c.dpad, Wc, twoout, AB);
    gathermax_kernel<<<16384 * c.out / 256, 256, 0, stream>>>(
        AB, idx, catb, cat_hi, cat_lo, xx, c.out, c.catoff, c.needxx);
  }
  gemmmax_kernel<<<dim3(8, 16, 16), 256, 0, stream>>>(cat_hi, cat_lo, W4h, W4l, part);
  zprep_kernel<<<16, 256, 0, stream>>>(part, y, F0w, F0b, F1w, F1b, L2b, zbuf,
                                       (float*)d_out);
  l0_kernel<<<dim3(8, 16), 256, 0, stream>>>(zbuf, L0, z1buf);
  l1l2_kernel<<<dim3(4, 16), 256, 0, stream>>>(z1buf, L1, L2w, (float*)d_out);
}

// Round 13
// 536.389 us; speedup vs baseline: 1.1608x; 1.1608x over previous
//
#include <hip/hip_runtime.h>
#include <cstddef>
#include <cstdint>

typedef __attribute__((ext_vector_type(8))) short bf16x8;
typedef __attribute__((ext_vector_type(4))) float f32x4;

__device__ __forceinline__ float lrelu_f(float v) { return v > 0.f ? v : 0.2f * v; }

__device__ __forceinline__ unsigned short f2bf_rne(float f) {
  unsigned u = __float_as_uint(f);
  return (unsigned short)((u + 0x7fffu + ((u >> 16) & 1u)) >> 16);
}
__device__ __forceinline__ float bf2f(unsigned short h) {
  return __uint_as_float((unsigned)h << 16);
}

// ------- prep: pad x [B,N,6] -> [B,N,16] (fp32 + bf16 hi/lo), compute xx -----
__global__ void prepx_kernel(const float* __restrict__ x, float* __restrict__ xpad,
                             unsigned short* __restrict__ xph,
                             unsigned short* __restrict__ xpl,
                             float* __restrict__ xx) {
  int p = blockIdx.x * 256 + threadIdx.x;  // 0..16383
  const float* xp = x + (size_t)p * 6;
  float v[6];
  float s = 0.f;
#pragma unroll
  for (int c = 0; c < 6; ++c) { v[c] = xp[c]; s = fmaf(v[c], v[c], s); }
  float* o = xpad + (size_t)p * 16;
  unsigned short* oh = xph + (size_t)p * 16;
  unsigned short* ol = xpl + (size_t)p * 16;
#pragma unroll
  for (int c = 0; c < 6; ++c) {
    o[c] = v[c];
    unsigned short h = f2bf_rne(v[c]);
    oh[c] = h;
    ol[c] = f2bf_rne(v[c] - bf2f(h));
  }
#pragma unroll
  for (int c = 6; c < 16; ++c) { o[c] = 0.f; oh[c] = 0; ol[c] = 0; }
  xx[p] = s;
}

// ---------------- Wc prep: [2out, dpad]; rows 0..out-1 = W_a, out.. = W_b - W_a
__global__ void wcprep_kernel(const float* __restrict__ W, float* __restrict__ Wc,
                              int out, int d, int dpad) {
  int i = blockIdx.x * 256 + threadIdx.x;
  if (i >= 2 * out * dpad) return;
  int j = i / dpad, c = i - j * dpad;
  float v = 0.f;
  if (c < d) {
    v = (j < out) ? W[j * 2 * d + c]
                  : (W[(j - out) * 2 * d + d + c] - W[(j - out) * 2 * d + c]);
  }
  Wc[i] = v;
}

// ---------------- W4 -> bf16 hi/lo split ------------------------------------
__global__ void w4prep_kernel(const float* __restrict__ W4,
                              unsigned short* __restrict__ W4h,
                              unsigned short* __restrict__ W4l) {
  int i = blockIdx.x * 256 + threadIdx.x;  // 0..524287
  float v = W4[i];
  unsigned short h = f2bf_rne(v);
  W4h[i] = h;
  W4l[i] = f2bf_rne(v - bf2f(h));
}

// ---- fused dist+top20: block = 16 rows x 1024 cols of one batch -------------
// S[i][j] = 2*dot(F_i,F_j) - xx_j  (row-constant -xx_i dropped: rank-invariant)
// dot via 3-pass bf16 MFMA (hh + hl + lh). Then ballot-radix top-20 per row.
// R12: S aliases the A-staging buffer (A-frags live in regs before S written)
//      -> 64.1 KB LDS, 2 blocks/CU. Topk probes: per-lane count + 5 bitplane
//      ballots (3x fewer VALU->SALU crossings) + early exit at count==20.
template <int DPAD, int KPAD>
__global__ __launch_bounds__(512) void disttopk_kernel(
    const unsigned short* __restrict__ Fh, const unsigned short* __restrict__ Fl,
    int fstride, int foff, const float* __restrict__ xx, int* __restrict__ idx) {
  constexpr int LSTR = KPAD + 8;   // ushorts; keeps 16B align, breaks bank aliasing
  constexpr int SSTR = 1026;       // floats; +2 pad -> S access 2-way only (free)
  __shared__ __align__(16) unsigned char smem[16 * SSTR * 4];  // 65,664 B
  unsigned short* rFh = (unsigned short*)smem;          // [16*LSTR], dies early
  unsigned short* rFl = rFh + 16 * LSTR;
  float* S = (float*)smem;                              // aliases rF region
  static_assert(2 * 16 * LSTR * 2 <= 16 * SSTR * 4, "rF must fit under S");
  int tid = threadIdx.x;
  int b = blockIdx.y, r0 = blockIdx.x * 16;
  int rowg0 = b * 1024 + r0;

  // stage the 16 A-rows (zero-padded to KPAD)
  constexpr int KC = KPAD / 8;
  for (int e = tid; e < 16 * KC; e += 512) {
    int row = e / KC, kc = e - row * KC;
    uint4 h = {0, 0, 0, 0}, l = {0, 0, 0, 0};
    if (kc * 8 < DPAD) {
      size_t src = (size_t)(rowg0 + row) * fstride + foff + kc * 8;
      h = *(const uint4*)(Fh + src);
      l = *(const uint4*)(Fl + src);
    }
    *(uint4*)(rFh + row * LSTR + kc * 8) = h;
    *(uint4*)(rFl + row * LSTR + kc * 8) = l;
  }
  __syncthreads();

  int wave = tid >> 6, lane = tid & 63;
  int l15 = lane & 15, l4 = lane >> 4;

  // A-fragments: loop-invariant, load once from LDS into registers
  bf16x8 ah[KPAD / 32], al[KPAD / 32];
#pragma unroll
  for (int ks = 0; ks < KPAD / 32; ++ks) {
    ah[ks] = *(const bf16x8*)(rFh + l15 * LSTR + ks * 32 + l4 * 8);
    al[ks] = *(const bf16x8*)(rFl + l15 * LSTR + ks * 32 + l4 * 8);
  }
  __syncthreads();  // all waves done reading rF before S overwrites it

  const float* xxb = xx + b * 1024;

  // 4 pair-iterations; wave w owns cols {p*256 + w*16 .. +15} and {+128}.
  for (int p = 0; p < 4; ++p) {
    int c0 = p * 256 + wave * 16;
    int c1 = c0 + 128;
    size_t sb0 = (size_t)(b * 1024 + c0 + l15) * fstride + foff + l4 * 8;
    size_t sb1 = (size_t)(b * 1024 + c1 + l15) * fstride + foff + l4 * 8;
    f32x4 aA0 = {}, aB0 = {}, aA1 = {}, aB1 = {};
#pragma unroll
    for (int ks = 0; ks < KPAD / 32; ++ks) {
      bf16x8 bh0 = {}, bl0 = {}, bh1 = {}, bl1 = {};
      if (ks * 32 + l4 * 8 < DPAD) {  // guards only layer0's K-pad region
        bh0 = *(const bf16x8*)(Fh + sb0 + ks * 32);
        bl0 = *(const bf16x8*)(Fl + sb0 + ks * 32);
        bh1 = *(const bf16x8*)(Fh + sb1 + ks * 32);
        bl1 = *(const bf16x8*)(Fl + sb1 + ks * 32);
      }
      aA0 = __builtin_amdgcn_mfma_f32_16x16x32_bf16(ah[ks], bh0, aA0, 0, 0, 0);
      aA1 = __builtin_amdgcn_mfma_f32_16x16x32_bf16(ah[ks], bh1, aA1, 0, 0, 0);
      aB0 = __builtin_amdgcn_mfma_f32_16x16x32_bf16(ah[ks], bl0, aB0, 0, 0, 0);
      aB1 = __builtin_amdgcn_mfma_f32_16x16x32_bf16(ah[ks], bl1, aB1, 0, 0, 0);
      aA0 = __builtin_amdgcn_mfma_f32_16x16x32_bf16(al[ks], bh0, aA0, 0, 0, 0);
      aA1 = __builtin_amdgcn_mfma_f32_16x16x32_bf16(al[ks], bh1, aA1, 0, 0, 0);
    }
    float xc0 = xxb[c0 + l15], xc1 = xxb[c1 + l15];
#pragma unroll
    for (int r = 0; r < 4; ++r) {
      S[(l4 * 4 + r) * SSTR + c0 + l15] = 2.f * (aA0[r] + aB0[r]) - xc0;
      S[(l4 * 4 + r) * SSTR + c1 + l15] = 2.f * (aA1[r] + aB1[r]) - xc1;
    }
  }
  __syncthreads();

  // top-20 per row: wave handles rows {wave, wave+8}
  unsigned long long lanebit = 1ull << lane;
  for (int rr = wave; rr < 16; rr += 8) {
    unsigned u[16];
#pragma unroll
    for (int j = 0; j < 16; ++j) {
      unsigned bits = __float_as_uint(S[rr * SSTR + j * 64 + lane]);
      unsigned m = (unsigned)((int)bits >> 31);
      u[j] = bits ^ (m | 0x80000000u);  // order-preserving map
    }
    // bit-descent for T = 20th-largest key. Per-lane count (pure VALU) then
    // 5 bitplane ballots; early exit when count == 20 (set already exact).
    unsigned X = 0;
#pragma clang loop unroll(disable)
    for (int bit = 31; bit >= 0; --bit) {
      unsigned Xt = X | (1u << bit);
      int cnt = 0;
#pragma unroll
      for (int j = 0; j < 16; ++j) cnt += (int)(u[j] >= Xt);
      int c = 0;
#pragma unroll
      for (int k = 0; k < 5; ++k)
        c += (int)__popcll(__ballot((cnt >> k) & 1)) << k;
      if (c >= 20) {
        X = Xt;
        if (c == 20) break;
      }
    }
    const unsigned T = X;
    int* op = idx + (size_t)(rowg0 + rr) * 20;
    int base = 0;
#pragma unroll
    for (int j = 0; j < 16; ++j) {
      unsigned long long m = __ballot(u[j] > T);
      int before = __popcll(m & (lanebit - 1ull));
      if (m & lanebit) op[base + before] = j * 64 + lane;
      base += __popcll(m);
    }
#pragma unroll
    for (int j = 0; j < 16; ++j) {
      unsigned long long m = __ballot(u[j] == T);
      int before = __popcll(m & (lanebit - 1ull));
      int pos = base + before;
      if ((m & lanebit) && pos < 20) op[pos] = j * 64 + lane;
      base += __popcll(m);
    }
  }
}

// ---------------- AB = F @ Wc^T : [16384, 2out] --------------------------------
__global__ __launch_bounds__(256) void ab_kernel(
    const float* __restrict__ F, int stride, int off, int dpad,
    const float* __restrict__ Wc, int twoout, float* __restrict__ AB) {
  int pb = blockIdx.x * 64, cb = blockIdx.y * 64;
  __shared__ __align__(16) float As[16][68];
  __shared__ __align__(16) float Bs[16][68];
  int tid = threadIdx.x;
  int tx = tid & 15, ty = tid >> 4;
  int lp = tid >> 2, lk = (tid & 3) * 4;
  float acc[4][4] = {};
  for (int k0 = 0; k0 < dpad; k0 += 16) {
    float4 av = *(const float4*)(F + (size_t)(pb + lp) * stride + off + k0 + lk);
    float4 bv = *(const float4*)(Wc + (size_t)(cb + lp) * dpad + k0 + lk);
    __syncthreads();
    As[lk + 0][lp] = av.x; As[lk + 1][lp] = av.y; As[lk + 2][lp] = av.z; As[lk + 3][lp] = av.w;
    Bs[lk + 0][lp] = bv.x; Bs[lk + 1][lp] = bv.y; Bs[lk + 2][lp] = bv.z; Bs[lk + 3][lp] = bv.w;
    __syncthreads();
#pragma unroll
    for (int kk = 0; kk < 16; ++kk) {
      float4 a4 = *(const float4*)&As[kk][ty * 4];
      float4 b4 = *(const float4*)&Bs[kk][tx * 4];
      float ar[4] = {a4.x, a4.y, a4.z, a4.w};
      float br[4] = {b4.x, b4.y, b4.z, b4.w};
#pragma unroll
      for (int i = 0; i < 4; ++i)
#pragma unroll
        for (int j = 0; j < 4; ++j) acc[i][j] = fmaf(ar[i], br[j], acc[i][j]);
    }
  }
#pragma unroll
  for (int i = 0; i < 4; ++i) {
    float4 o = {acc[i][0], acc[i][1], acc[i][2], acc[i][3]};
    *(float4*)(AB + (size_t)(pb + ty * 4 + i) * twoout + cb + tx * 4) = o;
  }
}

// ------- out[p,o] = max_t lrelu(A[idx[p][t],o] + Bc[p,o]); bf16 hi/lo too ----
__global__ void gathermax_kernel(const float* __restrict__ AB, const int* __restrict__ idx,
                                 float* __restrict__ catb,
                                 unsigned short* __restrict__ cat_hi,
                                 unsigned short* __restrict__ cat_lo,
                                 float* __restrict__ xx,
                                 int out, int catoff, int needxx) {
  int tid = threadIdx.x;
  int q = tid / out, o = tid - q * out;
  int ppb = 256 / out;
  int p = blockIdx.x * ppb + q;  // global point 0..16383
  int twoout = out * 2;
  const int* ip = idx + (size_t)p * 20;
  float bias = AB[(size_t)p * twoout + out + o];
  int bbase = p & ~1023;
  float m = -3.402823466e38f;
#pragma unroll
  for (int t = 0; t < 20; ++t) {
    int j = ip[t];
    float v = AB[(size_t)(bbase + j) * twoout + o] + bias;
    v = v > 0.f ? v : 0.2f * v;
    m = fmaxf(m, v);
  }
  size_t ci = (size_t)p * 512 + catoff + o;
  catb[ci] = m;
  unsigned short h = f2bf_rne(m);
  cat_hi[ci] = h;
  cat_lo[ci] = f2bf_rne(m - bf2f(h));
  if (needxx) {
    __shared__ float buf[256];
    buf[tid] = m * m;
    __syncthreads();
    for (int s = out >> 1; s > 0; s >>= 1) {
      if (o < s) buf[tid] += buf[tid + s];
      __syncthreads();
    }
    if (o == 0) xx[p] = buf[tid];
  }
}

// ------- partial[b,nb,o] = max over 64-pt chunk of lrelu(W4 @ cat), bf16x3 MFMA
__global__ __launch_bounds__(256) void gemmmax_kernel(
    const unsigned short* __restrict__ cat_hi, const unsigned short* __restrict__ cat_lo,
    const unsigned short* __restrict__ W4h, const unsigned short* __restrict__ W4l,
    float* __restrict__ partial) {
  int b = blockIdx.z;
  int ob = blockIdx.x * 128;        // o-tile base
  int ny = blockIdx.y;              // n-chunk (64 points)
  int p0 = b * 1024 + ny * 64;      // global point base
  __shared__ __align__(16) unsigned short Ah[128 * 40];
  __shared__ __align__(16) unsigned short Al[128 * 40];
  __shared__ __align__(16) unsigned short Bh[64 * 40];
  __shared__ __align__(16) unsigned short Bl[64 * 40];
  int tid = threadIdx.x;
  int wave = tid >> 6, lane = tid & 63;
  int l15 = lane & 15, l4 = lane >> 4;

  int arow = tid >> 1, ac0 = (tid & 1) * 2;
  int brow = tid >> 2, bc = tid & 3;

  f32x4 acc[2][4] = {};

  for (int k0 = 0; k0 < 512; k0 += 32) {
    uint4 a0 = *(const uint4*)(W4h + (size_t)(ob + arow) * 512 + k0 + ac0 * 8);
    uint4 a1 = *(const uint4*)(W4h + (size_t)(ob + arow) * 512 + k0 + (ac0 + 1) * 8);
    uint4 al0 = *(const uint4*)(W4l + (size_t)(ob + arow) * 512 + k0 + ac0 * 8);
    uint4 al1 = *(const uint4*)(W4l + (size_t)(ob + arow) * 512 + k0 + (ac0 + 1) * 8);
    uint4 b0 = *(const uint4*)(cat_hi + (size_t)(p0 + brow) * 512 + k0 + bc * 8);
    uint4 bl0 = *(const uint4*)(cat_lo + (size_t)(p0 + brow) * 512 + k0 + bc * 8);
    __syncthreads();
    *(uint4*)(Ah + arow * 40 + ac0 * 8) = a0;
    *(uint4*)(Ah + arow * 40 + (ac0 + 1) * 8) = a1;
    *(uint4*)(Al + arow * 40 + ac0 * 8) = al0;
    *(uint4*)(Al + arow * 40 + (ac0 + 1) * 8) = al1;
    *(uint4*)(Bh + brow * 40 + bc * 8) = b0;
    *(uint4*)(Bl + brow * 40 + bc * 8) = bl0;
    __syncthreads();

    bf16x8 ah[2], alr[2], bh[4], blr[4];
#pragma unroll
    for (int m = 0; m < 2; ++m) {
      int r = wave * 32 + m * 16 + l15;
      ah[m] = *(const bf16x8*)(Ah + r * 40 + l4 * 8);
      alr[m] = *(const bf16x8*)(Al + r * 40 + l4 * 8);
    }
#pragma unroll
    for (int n = 0; n < 4; ++n) {
      int r = n * 16 + l15;
      bh[n] = *(const bf16x8*)(Bh + r * 40 + l4 * 8);
      blr[n] = *(const bf16x8*)(Bl + r * 40 + l4 * 8);
    }
#pragma unroll
    for (int m = 0; m < 2; ++m)
#pragma unroll
      for (int n = 0; n < 4; ++n) {
        acc[m][n] = __builtin_amdgcn_mfma_f32_16x16x32_bf16(ah[m], bh[n], acc[m][n], 0, 0, 0);
        acc[m][n] = __builtin_amdgcn_mfma_f32_16x16x32_bf16(ah[m], blr[n], acc[m][n], 0, 0, 0);
        acc[m][n] = __builtin_amdgcn_mfma_f32_16x16x32_bf16(alr[m], bh[n], acc[m][n], 0, 0, 0);
      }
  }

#pragma unroll
  for (int m = 0; m < 2; ++m)
#pragma unroll
    for (int r = 0; r < 4; ++r) {
      float v = lrelu_f(acc[m][0][r]);
      v = fmaxf(v, lrelu_f(acc[m][1][r]));
      v = fmaxf(v, lrelu_f(acc[m][2][r]));
      v = fmaxf(v, lrelu_f(acc[m][3][r]));
      v = fmaxf(v, __shfl_xor(v, 1));
      v = fmaxf(v, __shfl_xor(v, 2));
      v = fmaxf(v, __shfl_xor(v, 4));
      v = fmaxf(v, __shfl_xor(v, 8));
      if (l15 == 0)
        partial[((size_t)(b * 16 + ny) << 10) + ob + wave * 32 + m * 16 + l4 * 4 + r] = v;
    }
}

// ---- zprep: z[b][1088] = [maxpool(partial) | y-MLP]; seed out[b] = L2b ------
__global__ __launch_bounds__(256) void zprep_kernel(
    const float* __restrict__ partial, const float* __restrict__ y,
    const float* __restrict__ F0w, const float* __restrict__ F0b,
    const float* __restrict__ F1w, const float* __restrict__ F1b,
    const float* __restrict__ L2b, float* __restrict__ zbuf,
    float* __restrict__ outp) {
  int b = blockIdx.x, tid = threadIdx.x;
  __shared__ float ye0[16];
  for (int o = tid; o < 1024; o += 256) {
    float m = -3.402823466e38f;
#pragma unroll
    for (int nb = 0; nb < 16; ++nb)
      m = fmaxf(m, partial[((size_t)(b * 16 + nb) << 10) + o]);
    zbuf[(size_t)b * 1088 + o] = m;
  }
  if (tid < 16) {
    float s = F0b[tid];
#pragma unroll
    for (int c = 0; c < 16; ++c) s = fmaf(y[b * 16 + c], F0w[tid * 16 + c], s);
    ye0[tid] = lrelu_f(s);
  }
  __syncthreads();
  if (tid < 64) {
    float s = F1b[tid];
#pragma unroll
    for (int c = 0; c < 16; ++c) s = fmaf(ye0[c], F1w[tid * 16 + c], s);
    zbuf[(size_t)b * 1088 + 1024 + tid] = lrelu_f(s);
  }
  if (tid == 0) outp[b] = L2b[0];
}

// ---- l0: z1[b][512] = lrelu(L0 @ z[b]); 4 threads per output row -----------
__global__ __launch_bounds__(256) void l0_kernel(
    const float* __restrict__ zbuf, const float* __restrict__ L0,
    float* __restrict__ z1buf) {
  int jt = blockIdx.x, b = blockIdx.y, tid = threadIdx.x;
  __shared__ __align__(16) float zs[1088];
  // 1088 floats = 272 float4; 256 threads cover 1024, tid<16 cover the tail.
  *(float4*)&zs[tid * 4] = *(const float4*)&zbuf[(size_t)b * 1088 + tid * 4];
  if (tid < 16)
    *(float4*)&zs[1024 + tid * 4] =
        *(const float4*)&zbuf[(size_t)b * 1088 + 1024 + tid * 4];
  __syncthreads();
  int j = jt * 64 + (tid >> 2), sl = tid & 3;
  const float4* Lr = (const float4*)(L0 + (size_t)j * 1088 + sl * 272);
  const float4* zr = (const float4*)(zs + sl * 272);
  float s = 0.f;
#pragma unroll 8
  for (int c = 0; c < 68; ++c) {
    float4 w = Lr[c], zz = zr[c];
    s = fmaf(w.x, zz.x, s); s = fmaf(w.y, zz.y, s);
    s = fmaf(w.z, zz.z, s); s = fmaf(w.w, zz.w, s);
  }
  s += __shfl_xor(s, 1);
  s += __shfl_xor(s, 2);
  if (sl == 0) z1buf[(size_t)b * 512 + j] = lrelu_f(s);
}

// ---- l1l2: z2 = lrelu(L1 @ z1); out[b] += sum z2*L2w (atomic per block) -----
__global__ __launch_bounds__(256) void l1l2_kernel(
    const float* __restrict__ z1buf, const float* __restrict__ L1,
    const float* __restrict__ L2w, float* __restrict__ outp) {
  int jt = blockIdx.x, b = blockIdx.y, tid = threadIdx.x;
  __shared__ __align__(16) float zs[512];
  if (tid < 128) *(float4*)&zs[tid * 4] = *(const float4*)&z1buf[(size_t)b * 512 + tid * 4];
  __syncthreads();
  int j = jt * 64 + (tid >> 2), sl = tid & 3;
  const float4* Lr = (const float4*)(L1 + (size_t)j * 512 + sl * 128);
  const float4* zr = (const float4*)(zs + sl * 128);
  float s = 0.f;
#pragma unroll 8
  for (int c = 0; c < 32; ++c) {
    float4 w = Lr[c], zz = zr[c];
    s = fmaf(w.x, zz.x, s); s = fmaf(w.y, zz.y, s);
    s = fmaf(w.z, zz.z, s); s = fmaf(w.w, zz.w, s);
  }
  s += __shfl_xor(s, 1);
  s += __shfl_xor(s, 2);
  float v = (sl == 0) ? lrelu_f(s) * L2w[j] : 0.f;
#pragma unroll
  for (int m = 1; m < 64; m <<= 1) v += __shfl_xor(v, m);
  __shared__ float wsum[4];
  if ((tid & 63) == 0) wsum[tid >> 6] = v;
  __syncthreads();
  if (tid == 0) atomicAdd(&outp[b], wsum[0] + wsum[1] + wsum[2] + wsum[3]);
}

extern "C" void kernel_launch(void* const* d_in, const int* in_sizes, int n_in,
                              void* d_out, int out_size, void* d_ws, size_t ws_size,
                              hipStream_t stream) {
  const float* x = (const float*)d_in[0];
  const float* y = (const float*)d_in[1];
  const float* Wl[4] = {(const float*)d_in[2], (const float*)d_in[3],
                        (const float*)d_in[4], (const float*)d_in[5]};
  const float* W4 = (const float*)d_in[6];
  const float* L0 = (const float*)d_in[7];
  const float* L1 = (const float*)d_in[8];
  const float* L2w = (const float*)d_in[9];
  const float* L2b = (const float*)d_in[10];
  const float* F0w = (const float*)d_in[11];
  const float* F0b = (const float*)d_in[12];
  const float* F1w = (const float*)d_in[13];
  const float* F1b = (const float*)d_in[14];

  float* ws = (float*)d_ws;
  float* xpad = ws;                     // 16384*16      = 262144
  float* catb = ws + 262144;            // 16384*512     = 8388608
  // former D region (now unused) hosts the bf16 split of xpad:
  unsigned short* xph = (unsigned short*)(ws + 8650752);   // 16384*16 u16
  unsigned short* xpl = (unsigned short*)(ws + 8781824);   // 16384*16 u16
  float* AB   = ws + 25427968;          // 16384*512     = 8388608
  int*   idx  = (int*)(ws + 33816576);  // 16384*20      = 327680
  float* xx   = ws + 34144256;          // 16384
  float* Wc   = ws + 34160640;          // 512*128       = 65536
  float* part = ws + 34226176;          // 16*16*1024    = 262144
  unsigned short* cat_hi = (unsigned short*)(ws + 34488320);  // 16384*512 u16
  unsigned short* cat_lo = (unsigned short*)(ws + 38682624);  // 16384*512 u16
  unsigned short* W4h    = (unsigned short*)(ws + 42876928);  // 1024*512 u16
  unsigned short* W4l    = (unsigned short*)(ws + 43139072);  // 1024*512 u16
  float* zbuf  = ws + 43401216;         // 16*1088 = 17408
  float* z1buf = ws + 43418624;         // 16*512  = 8192

  prepx_kernel<<<64, 256, 0, stream>>>(x, xpad, xph, xpl, xx);
  w4prep_kernel<<<2048, 256, 0, stream>>>(W4, W4h, W4l);

  struct LC { const float* F; int stride, off, d, dpad, out, catoff, needxx; };
  LC lc[4] = {
      {xpad, 16, 0, 6, 16, 64, 0, 1},
      {catb, 512, 0, 64, 64, 64, 64, 1},
      {catb, 512, 64, 64, 64, 128, 128, 1},
      {catb, 512, 128, 128, 128, 256, 256, 0},
  };
  for (int l = 0; l < 4; ++l) {
    LC c = lc[l];
    int twoout = c.out * 2;
    wcprep_kernel<<<(2 * c.out * c.dpad + 255) / 256, 256, 0, stream>>>(
        Wl[l], Wc, c.out, c.d, c.dpad);
    if (l == 0)
      disttopk_kernel<16, 32><<<dim3(64, 16), 512, 0, stream>>>(
          xph, xpl, 16, 0, xx, idx);
    else if (l == 3)
      disttopk_kernel<128, 128><<<dim3(64, 16), 512, 0, stream>>>(
          cat_hi, cat_lo, 512, 128, xx, idx);
    else
      disttopk_kernel<64, 64><<<dim3(64, 16), 512, 0, stream>>>(
          cat_hi, cat_lo, 512, (l == 1) ? 0 : 64, xx, idx);
    ab_kernel<<<dim3(256, twoout / 64), 256, 0, stream>>>(
        c.F, c.stride, c.off, c.dpad, Wc, twoout, AB);
    gathermax_kernel<<<16384 * c.out / 256, 256, 0, stream>>>(
        AB, idx, catb, cat_hi, cat_lo, xx, c.out, c.catoff, c.needxx);
  }
  gemmmax_kernel<<<dim3(8, 16, 16), 256, 0, stream>>>(cat_hi, cat_lo, W4h, W4l, part);
  zprep_kernel<<<16, 256, 0, stream>>>(part, y, F0w, F0b, F1w, F1b, L2b, zbuf,
                                       (float*)d_out);
  l0_kernel<<<dim3(8, 16), 256, 0, stream>>>(zbuf, L0, z1buf);
  l1l2_kernel<<<dim3(4, 16), 256, 0, stream>>>(z1buf, L1, L2w, (float*)d_out);
}

// Round 14
// 504.435 us; speedup vs baseline: 1.2343x; 1.0633x over previous
//
#include <hip/hip_runtime.h>
#include <cstddef>
#include <cstdint>

typedef __attribute__((ext_vector_type(8))) short bf16x8;
typedef __attribute__((ext_vector_type(4))) float f32x4;

__device__ __forceinline__ float lrelu_f(float v) { return v > 0.f ? v : 0.2f * v; }

__device__ __forceinline__ unsigned short f2bf_rne(float f) {
  unsigned u = __float_as_uint(f);
  return (unsigned short)((u + 0x7fffu + ((u >> 16) & 1u)) >> 16);
}
__device__ __forceinline__ float bf2f(unsigned short h) {
  return __uint_as_float((unsigned)h << 16);
}

// ------- prep: pad x [B,N,6] -> [B,N,16] (fp32 + bf16 hi/lo), compute xx -----
__global__ void prepx_kernel(const float* __restrict__ x, float* __restrict__ xpad,
                             unsigned short* __restrict__ xph,
                             unsigned short* __restrict__ xpl,
                             float* __restrict__ xx) {
  int p = blockIdx.x * 256 + threadIdx.x;  // 0..16383
  const float* xp = x + (size_t)p * 6;
  float v[6];
  float s = 0.f;
#pragma unroll
  for (int c = 0; c < 6; ++c) { v[c] = xp[c]; s = fmaf(v[c], v[c], s); }
  float* o = xpad + (size_t)p * 16;
  unsigned short* oh = xph + (size_t)p * 16;
  unsigned short* ol = xpl + (size_t)p * 16;
#pragma unroll
  for (int c = 0; c < 6; ++c) {
    o[c] = v[c];
    unsigned short h = f2bf_rne(v[c]);
    oh[c] = h;
    ol[c] = f2bf_rne(v[c] - bf2f(h));
  }
#pragma unroll
  for (int c = 6; c < 16; ++c) { o[c] = 0.f; oh[c] = 0; ol[c] = 0; }
  xx[p] = s;
}

// ---------------- Wc prep: [2out, dpad]; rows 0..out-1 = W_a, out.. = W_b - W_a
__global__ void wcprep_kernel(const float* __restrict__ W, float* __restrict__ Wc,
                              int out, int d, int dpad) {
  int i = blockIdx.x * 256 + threadIdx.x;
  if (i >= 2 * out * dpad) return;
  int j = i / dpad, c = i - j * dpad;
  float v = 0.f;
  if (c < d) {
    v = (j < out) ? W[j * 2 * d + c]
                  : (W[(j - out) * 2 * d + d + c] - W[(j - out) * 2 * d + c]);
  }
  Wc[i] = v;
}

// ---------------- W4 -> bf16 hi/lo split ------------------------------------
__global__ void w4prep_kernel(const float* __restrict__ W4,
                              unsigned short* __restrict__ W4h,
                              unsigned short* __restrict__ W4l) {
  int i = blockIdx.x * 256 + threadIdx.x;  // 0..524287
  float v = W4[i];
  unsigned short h = f2bf_rne(v);
  W4h[i] = h;
  W4l[i] = f2bf_rne(v - bf2f(h));
}

// ---- dist via tiled 3-pass bf16 MFMA GEMM -> D[b,i,j] = 2*dot - xx_j --------
// 64x64 tile, BK=32, LDS-staged A & B (hi/lo) with coalesced loads. 20.5 KB LDS.
template <int DPAD, int KPAD>
__global__ __launch_bounds__(256) void distmfma_kernel(
    const unsigned short* __restrict__ Fh, const unsigned short* __restrict__ Fl,
    int fstride, int foff, const float* __restrict__ xx, float* __restrict__ D) {
  __shared__ __align__(16) unsigned short Ah[64 * 40];
  __shared__ __align__(16) unsigned short Al[64 * 40];
  __shared__ __align__(16) unsigned short Bh[64 * 40];
  __shared__ __align__(16) unsigned short Bl[64 * 40];
  int b = blockIdx.z;
  int rowbase = blockIdx.y * 64, colbase = blockIdx.x * 64;
  int tid = threadIdx.x;
  int wave = tid >> 6, lane = tid & 63;
  int l15 = lane & 15, l4 = lane >> 4;
  int srow = tid >> 2, sc = tid & 3;  // staging: row 0..63, 8-elem chunk 0..3

  f32x4 accA[4] = {}, accB[4] = {};

  for (int k0 = 0; k0 < KPAD; k0 += 32) {
    uint4 va_h = {0, 0, 0, 0}, va_l = {0, 0, 0, 0};
    uint4 vb_h = {0, 0, 0, 0}, vb_l = {0, 0, 0, 0};
    if (k0 + sc * 8 < DPAD) {  // guards only layer0's K-pad region
      size_t sa = (size_t)(b * 1024 + rowbase + srow) * fstride + foff + k0 + sc * 8;
      size_t sb = (size_t)(b * 1024 + colbase + srow) * fstride + foff + k0 + sc * 8;
      va_h = *(const uint4*)(Fh + sa);
      va_l = *(const uint4*)(Fl + sa);
      vb_h = *(const uint4*)(Fh + sb);
      vb_l = *(const uint4*)(Fl + sb);
    }
    __syncthreads();
    *(uint4*)(Ah + srow * 40 + sc * 8) = va_h;
    *(uint4*)(Al + srow * 40 + sc * 8) = va_l;
    *(uint4*)(Bh + srow * 40 + sc * 8) = vb_h;
    *(uint4*)(Bl + srow * 40 + sc * 8) = vb_l;
    __syncthreads();

    bf16x8 a_h = *(const bf16x8*)(Ah + (wave * 16 + l15) * 40 + l4 * 8);
    bf16x8 a_l = *(const bf16x8*)(Al + (wave * 16 + l15) * 40 + l4 * 8);
#pragma unroll
    for (int n = 0; n < 4; ++n) {
      bf16x8 b_h = *(const bf16x8*)(Bh + (n * 16 + l15) * 40 + l4 * 8);
      bf16x8 b_l = *(const bf16x8*)(Bl + (n * 16 + l15) * 40 + l4 * 8);
      accA[n] = __builtin_amdgcn_mfma_f32_16x16x32_bf16(a_h, b_h, accA[n], 0, 0, 0);
      accB[n] = __builtin_amdgcn_mfma_f32_16x16x32_bf16(a_h, b_l, accB[n], 0, 0, 0);
      accA[n] = __builtin_amdgcn_mfma_f32_16x16x32_bf16(a_l, b_h, accA[n], 0, 0, 0);
    }
  }

  size_t Dbase = ((size_t)b << 20);
#pragma unroll
  for (int n = 0; n < 4; ++n) {
    int col = colbase + n * 16 + l15;
    float xc = xx[b * 1024 + col];
#pragma unroll
    for (int r = 0; r < 4; ++r) {
      int rowi = rowbase + wave * 16 + l4 * 4 + r;
      D[Dbase + (size_t)rowi * 1024 + col] = 2.f * (accA[n][r] + accB[n][r]) - xc;
    }
  }
}

// ---- top-20 per row (standalone): ballot-radix bit-descent, wave per row ----
// Per-lane count (VALU) + 5 bitplane ballots; early exit at count==20.
__global__ __launch_bounds__(256) void topk_kernel(const float* __restrict__ D,
                                                   int* __restrict__ idx) {
  int wv = threadIdx.x >> 6, lane = threadIdx.x & 63;
  int row = blockIdx.x * 4 + wv;  // 0..16383 (batch*1024 + n)
  const float* Dr = D + (size_t)row * 1024;
  unsigned u[16];
#pragma unroll
  for (int j = 0; j < 16; ++j) {
    unsigned bits = __float_as_uint(Dr[j * 64 + lane]);
    unsigned m = (unsigned)((int)bits >> 31);
    u[j] = bits ^ (m | 0x80000000u);  // order-preserving map
  }
  unsigned X = 0;
#pragma clang loop unroll(disable)
  for (int bit = 31; bit >= 0; --bit) {
    unsigned Xt = X | (1u << bit);
    int cnt = 0;
#pragma unroll
    for (int j = 0; j < 16; ++j) cnt += (int)(u[j] >= Xt);
    int c = 0;
#pragma unroll
    for (int k = 0; k < 5; ++k)
      c += (int)__popcll(__ballot((cnt >> k) & 1)) << k;
    if (c >= 20) {
      X = Xt;
      if (c == 20) break;
    }
  }
  const unsigned T = X;
  unsigned long long lanebit = 1ull << lane;
  int* op = idx + (size_t)row * 20;
  int base = 0;
#pragma unroll
  for (int j = 0; j < 16; ++j) {
    unsigned long long m = __ballot(u[j] > T);
    int before = __popcll(m & (lanebit - 1ull));
    if (m & lanebit) op[base + before] = j * 64 + lane;
    base += __popcll(m);
  }
#pragma unroll
  for (int j = 0; j < 16; ++j) {
    unsigned long long m = __ballot(u[j] == T);
    int before = __popcll(m & (lanebit - 1ull));
    int pos = base + before;
    if ((m & lanebit) && pos < 20) op[pos] = j * 64 + lane;
    base += __popcll(m);
  }
}

// ---------------- AB = F @ Wc^T : [16384, 2out] --------------------------------
__global__ __launch_bounds__(256) void ab_kernel(
    const float* __restrict__ F, int stride, int off, int dpad,
    const float* __restrict__ Wc, int twoout, float* __restrict__ AB) {
  int pb = blockIdx.x * 64, cb = blockIdx.y * 64;
  __shared__ __align__(16) float As[16][68];
  __shared__ __align__(16) float Bs[16][68];
  int tid = threadIdx.x;
  int tx = tid & 15, ty = tid >> 4;
  int lp = tid >> 2, lk = (tid & 3) * 4;
  float acc[4][4] = {};
  for (int k0 = 0; k0 < dpad; k0 += 16) {
    float4 av = *(const float4*)(F + (size_t)(pb + lp) * stride + off + k0 + lk);
    float4 bv = *(const float4*)(Wc + (size_t)(cb + lp) * dpad + k0 + lk);
    __syncthreads();
    As[lk + 0][lp] = av.x; As[lk + 1][lp] = av.y; As[lk + 2][lp] = av.z; As[lk + 3][lp] = av.w;
    Bs[lk + 0][lp] = bv.x; Bs[lk + 1][lp] = bv.y; Bs[lk + 2][lp] = bv.z; Bs[lk + 3][lp] = bv.w;
    __syncthreads();
#pragma unroll
    for (int kk = 0; kk < 16; ++kk) {
      float4 a4 = *(const float4*)&As[kk][ty * 4];
      float4 b4 = *(const float4*)&Bs[kk][tx * 4];
      float ar[4] = {a4.x, a4.y, a4.z, a4.w};
      float br[4] = {b4.x, b4.y, b4.z, b4.w};
#pragma unroll
      for (int i = 0; i < 4; ++i)
#pragma unroll
        for (int j = 0; j < 4; ++j) acc[i][j] = fmaf(ar[i], br[j], acc[i][j]);
    }
  }
#pragma unroll
  for (int i = 0; i < 4; ++i) {
    float4 o = {acc[i][0], acc[i][1], acc[i][2], acc[i][3]};
    *(float4*)(AB + (size_t)(pb + ty * 4 + i) * twoout + cb + tx * 4) = o;
  }
}

// ------- out[p,o] = max_t lrelu(A[idx[p][t],o] + Bc[p,o]); bf16 hi/lo too ----
__global__ void gathermax_kernel(const float* __restrict__ AB, const int* __restrict__ idx,
                                 float* __restrict__ catb,
                                 unsigned short* __restrict__ cat_hi,
                                 unsigned short* __restrict__ cat_lo,
                                 float* __restrict__ xx,
                                 int out, int catoff, int needxx) {
  int tid = threadIdx.x;
  int q = tid / out, o = tid - q * out;
  int ppb = 256 / out;
  int p = blockIdx.x * ppb + q;  // global point 0..16383
  int twoout = out * 2;
  const int* ip = idx + (size_t)p * 20;
  float bias = AB[(size_t)p * twoout + out + o];
  int bbase = p & ~1023;
  float m = -3.402823466e38f;
#pragma unroll
  for (int t = 0; t < 20; ++t) {
    int j = ip[t];
    float v = AB[(size_t)(bbase + j) * twoout + o] + bias;
    v = v > 0.f ? v : 0.2f * v;
    m = fmaxf(m, v);
  }
  size_t ci = (size_t)p * 512 + catoff + o;
  catb[ci] = m;
  unsigned short h = f2bf_rne(m);
  cat_hi[ci] = h;
  cat_lo[ci] = f2bf_rne(m - bf2f(h));
  if (needxx) {
    __shared__ float buf[256];
    buf[tid] = m * m;
    __syncthreads();
    for (int s = out >> 1; s > 0; s >>= 1) {
      if (o < s) buf[tid] += buf[tid + s];
      __syncthreads();
    }
    if (o == 0) xx[p] = buf[tid];
  }
}

// ------- partial[b,nb,o] = max over 64-pt chunk of lrelu(W4 @ cat), bf16x3 MFMA
__global__ __launch_bounds__(256) void gemmmax_kernel(
    const unsigned short* __restrict__ cat_hi, const unsigned short* __restrict__ cat_lo,
    const unsigned short* __restrict__ W4h, const unsigned short* __restrict__ W4l,
    float* __restrict__ partial) {
  int b = blockIdx.z;
  int ob = blockIdx.x * 128;        // o-tile base
  int ny = blockIdx.y;              // n-chunk (64 points)
  int p0 = b * 1024 + ny * 64;      // global point base
  __shared__ __align__(16) unsigned short Ah[128 * 40];
  __shared__ __align__(16) unsigned short Al[128 * 40];
  __shared__ __align__(16) unsigned short Bh[64 * 40];
  __shared__ __align__(16) unsigned short Bl[64 * 40];
  int tid = threadIdx.x;
  int wave = tid >> 6, lane = tid & 63;
  int l15 = lane & 15, l4 = lane >> 4;

  int arow = tid >> 1, ac0 = (tid & 1) * 2;
  int brow = tid >> 2, bc = tid & 3;

  f32x4 acc[2][4] = {};

  for (int k0 = 0; k0 < 512; k0 += 32) {
    uint4 a0 = *(const uint4*)(W4h + (size_t)(ob + arow) * 512 + k0 + ac0 * 8);
    uint4 a1 = *(const uint4*)(W4h + (size_t)(ob + arow) * 512 + k0 + (ac0 + 1) * 8);
    uint4 al0 = *(const uint4*)(W4l + (size_t)(ob + arow) * 512 + k0 + ac0 * 8);
    uint4 al1 = *(const uint4*)(W4l + (size_t)(ob + arow) * 512 + k0 + (ac0 + 1) * 8);
    uint4 b0 = *(const uint4*)(cat_hi + (size_t)(p0 + brow) * 512 + k0 + bc * 8);
    uint4 bl0 = *(const uint4*)(cat_lo + (size_t)(p0 + brow) * 512 + k0 + bc * 8);
    __syncthreads();
    *(uint4*)(Ah + arow * 40 + ac0 * 8) = a0;
    *(uint4*)(Ah + arow * 40 + (ac0 + 1) * 8) = a1;
    *(uint4*)(Al + arow * 40 + ac0 * 8) = al0;
    *(uint4*)(Al + arow * 40 + (ac0 + 1) * 8) = al1;
    *(uint4*)(Bh + brow * 40 + bc * 8) = b0;
    *(uint4*)(Bl + brow * 40 + bc * 8) = bl0;
    __syncthreads();

    bf16x8 ah[2], alr[2], bh[4], blr[4];
#pragma unroll
    for (int m = 0; m < 2; ++m) {
      int r = wave * 32 + m * 16 + l15;
      ah[m] = *(const bf16x8*)(Ah + r * 40 + l4 * 8);
      alr[m] = *(const bf16x8*)(Al + r * 40 + l4 * 8);
    }
#pragma unroll
    for (int n = 0; n < 4; ++n) {
      int r = n * 16 + l15;
      bh[n] = *(const bf16x8*)(Bh + r * 40 + l4 * 8);
      blr[n] = *(const bf16x8*)(Bl + r * 40 + l4 * 8);
    }
#pragma unroll
    for (int m = 0; m < 2; ++m)
#pragma unroll
      for (int n = 0; n < 4; ++n) {
        acc[m][n] = __builtin_amdgcn_mfma_f32_16x16x32_bf16(ah[m], bh[n], acc[m][n], 0, 0, 0);
        acc[m][n] = __builtin_amdgcn_mfma_f32_16x16x32_bf16(ah[m], blr[n], acc[m][n], 0, 0, 0);
        acc[m][n] = __builtin_amdgcn_mfma_f32_16x16x32_bf16(alr[m], bh[n], acc[m][n], 0, 0, 0);
      }
  }

#pragma unroll
  for (int m = 0; m < 2; ++m)
#pragma unroll
    for (int r = 0; r < 4; ++r) {
      float v = lrelu_f(acc[m][0][r]);
      v = fmaxf(v, lrelu_f(acc[m][1][r]));
      v = fmaxf(v, lrelu_f(acc[m][2][r]));
      v = fmaxf(v, lrelu_f(acc[m][3][r]));
      v = fmaxf(v, __shfl_xor(v, 1));
      v = fmaxf(v, __shfl_xor(v, 2));
      v = fmaxf(v, __shfl_xor(v, 4));
      v = fmaxf(v, __shfl_xor(v, 8));
      if (l15 == 0)
        partial[((size_t)(b * 16 + ny) << 10) + ob + wave * 32 + m * 16 + l4 * 4 + r] = v;
    }
}

// ---- zprep: z[b][1088] = [maxpool(partial) | y-MLP]; seed out[b] = L2b ------
__global__ __launch_bounds__(256) void zprep_kernel(
    const float* __restrict__ partial, const float* __restrict__ y,
    const float* __restrict__ F0w, const float* __restrict__ F0b,
    const float* __restrict__ F1w, const float* __restrict__ F1b,
    const float* __restrict__ L2b, float* __restrict__ zbuf,
    float* __restrict__ outp) {
  int b = blockIdx.x, tid = threadIdx.x;
  __shared__ float ye0[16];
  for (int o = tid; o < 1024; o += 256) {
    float m = -3.402823466e38f;
#pragma unroll
    for (int nb = 0; nb < 16; ++nb)
      m = fmaxf(m, partial[((size_t)(b * 16 + nb) << 10) + o]);
    zbuf[(size_t)b * 1088 + o] = m;
  }
  if (tid < 16) {
    float s = F0b[tid];
#pragma unroll
    for (int c = 0; c < 16; ++c) s = fmaf(y[b * 16 + c], F0w[tid * 16 + c], s);
    ye0[tid] = lrelu_f(s);
  }
  __syncthreads();
  if (tid < 64) {
    float s = F1b[tid];
#pragma unroll
    for (int c = 0; c < 16; ++c) s = fmaf(ye0[c], F1w[tid * 16 + c], s);
    zbuf[(size_t)b * 1088 + 1024 + tid] = lrelu_f(s);
  }
  if (tid == 0) outp[b] = L2b[0];
}

// ---- l0: z1[b][512] = lrelu(L0 @ z[b]); 4 threads per output row -----------
__global__ __launch_bounds__(256) void l0_kernel(
    const float* __restrict__ zbuf, const float* __restrict__ L0,
    float* __restrict__ z1buf) {
  int jt = blockIdx.x, b = blockIdx.y, tid = threadIdx.x;
  __shared__ __align__(16) float zs[1088];
  // 1088 floats = 272 float4; 256 threads cover 1024, tid<16 cover the tail.
  *(float4*)&zs[tid * 4] = *(const float4*)&zbuf[(size_t)b * 1088 + tid * 4];
  if (tid < 16)
    *(float4*)&zs[1024 + tid * 4] =
        *(const float4*)&zbuf[(size_t)b * 1088 + 1024 + tid * 4];
  __syncthreads();
  int j = jt * 64 + (tid >> 2), sl = tid & 3;
  const float4* Lr = (const float4*)(L0 + (size_t)j * 1088 + sl * 272);
  const float4* zr = (const float4*)(zs + sl * 272);
  float s = 0.f;
#pragma unroll 8
  for (int c = 0; c < 68; ++c) {
    float4 w = Lr[c], zz = zr[c];
    s = fmaf(w.x, zz.x, s); s = fmaf(w.y, zz.y, s);
    s = fmaf(w.z, zz.z, s); s = fmaf(w.w, zz.w, s);
  }
  s += __shfl_xor(s, 1);
  s += __shfl_xor(s, 2);
  if (sl == 0) z1buf[(size_t)b * 512 + j] = lrelu_f(s);
}

// ---- l1l2: z2 = lrelu(L1 @ z1); out[b] += sum z2*L2w (atomic per block) -----
__global__ __launch_bounds__(256) void l1l2_kernel(
    const float* __restrict__ z1buf, const float* __restrict__ L1,
    const float* __restrict__ L2w, float* __restrict__ outp) {
  int jt = blockIdx.x, b = blockIdx.y, tid = threadIdx.x;
  __shared__ __align__(16) float zs[512];
  if (tid < 128) *(float4*)&zs[tid * 4] = *(const float4*)&z1buf[(size_t)b * 512 + tid * 4];
  __syncthreads();
  int j = jt * 64 + (tid >> 2), sl = tid & 3;
  const float4* Lr = (const float4*)(L1 + (size_t)j * 512 + sl * 128);
  const float4* zr = (const float4*)(zs + sl * 128);
  float s = 0.f;
#pragma unroll 8
  for (int c = 0; c < 32; ++c) {
    float4 w = Lr[c], zz = zr[c];
    s = fmaf(w.x, zz.x, s); s = fmaf(w.y, zz.y, s);
    s = fmaf(w.z, zz.z, s); s = fmaf(w.w, zz.w, s);
  }
  s += __shfl_xor(s, 1);
  s += __shfl_xor(s, 2);
  float v = (sl == 0) ? lrelu_f(s) * L2w[j] : 0.f;
#pragma unroll
  for (int m = 1; m < 64; m <<= 1) v += __shfl_xor(v, m);
  __shared__ float wsum[4];
  if ((tid & 63) == 0) wsum[tid >> 6] = v;
  __syncthreads();
  if (tid == 0) atomicAdd(&outp[b], wsum[0] + wsum[1] + wsum[2] + wsum[3]);
}

extern "C" void kernel_launch(void* const* d_in, const int* in_sizes, int n_in,
                              void* d_out, int out_size, void* d_ws, size_t ws_size,
                              hipStream_t stream) {
  const float* x = (const float*)d_in[0];
  const float* y = (const float*)d_in[1];
  const float* Wl[4] = {(const float*)d_in[2], (const float*)d_in[3],
                        (const float*)d_in[4], (const float*)d_in[5]};
  const float* W4 = (const float*)d_in[6];
  const float* L0 = (const float*)d_in[7];
  const float* L1 = (const float*)d_in[8];
  const float* L2w = (const float*)d_in[9];
  const float* L2b = (const float*)d_in[10];
  const float* F0w = (const float*)d_in[11];
  const float* F0b = (const float*)d_in[12];
  const float* F1w = (const float*)d_in[13];
  const float* F1b = (const float*)d_in[14];

  float* ws = (float*)d_ws;
  float* xpad = ws;                     // 16384*16      = 262144
  float* catb = ws + 262144;            // 16384*512     = 8388608
  unsigned short* xph = (unsigned short*)(ws + 8650752);   // 16384*16 u16
  unsigned short* xpl = (unsigned short*)(ws + 8781824);   // 16384*16 u16
  // D: 16*1024*1024 fp32, lifetime dist->topk. AB aliases D (lifetime
  // ab->gathermax) — the two windows are disjoint within each layer.
  float* D    = ws + 8912896;           // 16777216 floats, ends 25690112
  float* AB   = D;                      // 16384*512 = 8388608 floats (subset)
  int*   idx  = (int*)(ws + 33816576);  // 16384*20      = 327680
  float* xx   = ws + 34144256;          // 16384
  float* Wc   = ws + 34160640;          // 512*128       = 65536
  float* part = ws + 34226176;          // 16*16*1024    = 262144
  unsigned short* cat_hi = (unsigned short*)(ws + 34488320);  // 16384*512 u16
  unsigned short* cat_lo = (unsigned short*)(ws + 38682624);  // 16384*512 u16
  unsigned short* W4h    = (unsigned short*)(ws + 42876928);  // 1024*512 u16
  unsigned short* W4l    = (unsigned short*)(ws + 43139072);  // 1024*512 u16
  float* zbuf  = ws + 43401216;         // 16*1088 = 17408
  float* z1buf = ws + 43418624;         // 16*512  = 8192

  prepx_kernel<<<64, 256, 0, stream>>>(x, xpad, xph, xpl, xx);
  w4prep_kernel<<<2048, 256, 0, stream>>>(W4, W4h, W4l);

  struct LC { const float* F; int stride, off, d, dpad, out, catoff, needxx; };
  LC lc[4] = {
      {xpad, 16, 0, 6, 16, 64, 0, 1},
      {catb, 512, 0, 64, 64, 64, 64, 1},
      {catb, 512, 64, 64, 64, 128, 128, 1},
      {catb, 512, 128, 128, 128, 256, 256, 0},
  };
  for (int l = 0; l < 4; ++l) {
    LC c = lc[l];
    int twoout = c.out * 2;
    wcprep_kernel<<<(2 * c.out * c.dpad + 255) / 256, 256, 0, stream>>>(
        Wl[l], Wc, c.out, c.d, c.dpad);
    if (l == 0)
      distmfma_kernel<16, 32><<<dim3(16, 16, 16), 256, 0, stream>>>(
          xph, xpl, 16, 0, xx, D);
    else if (l == 3)
      distmfma_kernel<128, 128><<<dim3(16, 16, 16), 256, 0, stream>>>(
          cat_hi, cat_lo, 512, 128, xx, D);
    else
      distmfma_kernel<64, 64><<<dim3(16, 16, 16), 256, 0, stream>>>(
          cat_hi, cat_lo, 512, (l == 1) ? 0 : 64, xx, D);
    topk_kernel<<<4096, 256, 0, stream>>>(D, idx);
    ab_kernel<<<dim3(256, twoout / 64), 256, 0, stream>>>(
        c.F, c.stride, c.off, c.dpad, Wc, twoout, AB);
    gathermax_kernel<<<16384 * c.out / 256, 256, 0, stream>>>(
        AB, idx, catb, cat_hi, cat_lo, xx, c.out, c.catoff, c.needxx);
  }
  gemmmax_kernel<<<dim3(8, 16, 16), 256, 0, stream>>>(cat_hi, cat_lo, W4h, W4l, part);
  zprep_kernel<<<16, 256, 0, stream>>>(part, y, F0w, F0b, F1w, F1b, L2b, zbuf,
                                       (float*)d_out);
  l0_kernel<<<dim3(8, 16), 256, 0, stream>>>(zbuf, L0, z1buf);
  l1l2_kernel<<<dim3(4, 16), 256, 0, stream>>>(z1buf, L1, L2w, (float*)d_out);
}